// Round 4
// baseline (186.490 us; speedup 1.0000x reference)
//
#include <hip/hip_runtime.h>

#define DEV static __device__ __forceinline__

using bf16x8 = __attribute__((ext_vector_type(8))) short;
using f32x4  = __attribute__((ext_vector_type(4))) float;
using f32x16 = __attribute__((ext_vector_type(16))) float;

DEV unsigned short f2bf(float f) {
  union { float f; unsigned u; } v; v.f = f;
  return (unsigned short)((v.u + 0x7fffu + ((v.u >> 16) & 1u)) >> 16);
}
DEV unsigned pk2(float lo, float hi) {
  return (unsigned)f2bf(lo) | ((unsigned)f2bf(hi) << 16);
}
// single-instruction packed fp32->bf16 (RNE)
DEV unsigned cvtpk(float lo, float hi) {
  unsigned r;
  asm("v_cvt_pk_bf16_f32 %0, %1, %2" : "=v"(r) : "v"(lo), "v"(hi));
  return r;
}
// swap: a_new=[a_lo,b_lo], b_new=[a_hi,b_hi] across lane halves
DEV void pl32swap(unsigned &a, unsigned &b) {
  asm("v_permlane32_swap_b32 %0, %1" : "+v"(a), "+v"(b));
}
DEV bf16x8 mk8(unsigned a, unsigned b, unsigned c, unsigned d) {
  union { unsigned u[4]; bf16x8 v; } t;
  t.u[0] = a; t.u[1] = b; t.u[2] = c; t.u[3] = d;
  return t.v;
}
DEV f32x4 mfma16(bf16x8 a, bf16x8 b, f32x4 c) {
  return __builtin_amdgcn_mfma_f32_16x16x32_bf16(a, b, c, 0, 0, 0);
}
DEV f32x16 mfma32(bf16x8 a, bf16x8 b, f32x16 c) {
  return __builtin_amdgcn_mfma_f32_32x32x16_bf16(a, b, c, 0, 0, 0);
}
DEV f32x16 zero16() {
  f32x16 z;
#pragma unroll
  for (int i = 0; i < 16; ++i) z[i] = 0.f;
  return z;
}

typedef const __attribute__((address_space(1))) unsigned int* gas1;
typedef __attribute__((address_space(3))) unsigned int* las3;
DEV void gl16(const void* g, void* l) {
  __builtin_amdgcn_global_load_lds((gas1)g, (las3)l, 16, 0, 0);
}

// ---------------------------------------------------------------------------
// fp32 -> bf16 pre-convert: x1(4M) x2(4M) Wq Wk Wv Wp (1M each) -> 12M ushort.
// ---------------------------------------------------------------------------
__global__ __launch_bounds__(256, 8)
void conv_bf16(const float* __restrict__ x1, const float* __restrict__ x2,
               const float* __restrict__ Wq, const float* __restrict__ Wk,
               const float* __restrict__ Wv, const float* __restrict__ Wp,
               unsigned short* __restrict__ o)
{
  size_t e = ((size_t)blockIdx.x * 256 + threadIdx.x) * 8;
  const float* s; size_t off;
  if (e < 4194304u)       { s = x1; off = e; }
  else if (e < 8388608u)  { s = x2; off = e - 4194304u; }
  else if (e < 9437184u)  { s = Wq; off = e - 8388608u; }
  else if (e < 10485760u) { s = Wk; off = e - 9437184u; }
  else if (e < 11534336u) { s = Wv; off = e - 10485760u; }
  else                    { s = Wp; off = e - 11534336u; }
  const float4* p = reinterpret_cast<const float4*>(s + off);
  float4 a = p[0], b = p[1];
  int4 r;
  r.x = pk2(a.x, a.y); r.y = pk2(a.z, a.w);
  r.z = pk2(b.x, b.y); r.w = pk2(b.z, b.w);
  *reinterpret_cast<int4*>(o + e) = r;
}

// ---------------------------------------------------------------------------
// Fused QKV GEMM (m97 structure), bf16 in.
// z=0 -> qproj fp32; z=1 -> kproj fp32; z=2 -> V^T bf16 [B,H,D,M].
// ---------------------------------------------------------------------------
__global__ __launch_bounds__(256, 2)
void gemm_qkv_bf(const unsigned short* __restrict__ xb,
                 float* __restrict__ qproj, float* __restrict__ kproj,
                 unsigned short* __restrict__ vtb)
{
  __shared__ short As[128 * 64];
  __shared__ short Bs[128 * 64];
  const int tid = threadIdx.x;
  const int l = tid & 63, w = tid >> 6;
  const int wr = w >> 1, wc = w & 1;
  const int z = blockIdx.z;
  const unsigned short* A = (z == 0) ? xb : (xb + 4194304);
  const unsigned short* W = xb + 8388608 + (size_t)z * 1048576;
  const int brow = blockIdx.y * 128, bcol = blockIdx.x * 128;

  const f32x4 zero = {0.f, 0.f, 0.f, 0.f};
  f32x4 acc[4][4];
#pragma unroll
  for (int mi = 0; mi < 4; ++mi)
#pragma unroll
    for (int ni = 0; ni < 4; ++ni) acc[mi][ni] = zero;

  const int srow = w * 32 + (l >> 3);
  const int scol = (l & 7) * 8;

  for (int kt = 0; kt < 16; ++kt) {
    const unsigned short* ga = A + (size_t)(brow + srow) * 1024 + kt * 64 + scol;
    const unsigned short* gb = W + (size_t)(bcol + srow) * 1024 + kt * 64 + scol;
#pragma unroll
    for (int i = 0; i < 4; ++i) {
      gl16(ga + (size_t)i * 8 * 1024, &As[(w * 32 + i * 8) * 64]);
      gl16(gb + (size_t)i * 8 * 1024, &Bs[(w * 32 + i * 8) * 64]);
    }
    __syncthreads();
#pragma unroll
    for (int kk = 0; kk < 2; ++kk) {
      const int k0 = kk * 32 + ((l >> 4) << 3);
      bf16x8 af[4], bfr[4];
#pragma unroll
      for (int mi = 0; mi < 4; ++mi)
        af[mi] = *reinterpret_cast<const bf16x8*>(
            &As[((wr << 6) + (mi << 4) + (l & 15)) * 64 + k0]);
#pragma unroll
      for (int ni = 0; ni < 4; ++ni)
        bfr[ni] = *reinterpret_cast<const bf16x8*>(
            &Bs[((wc << 6) + (ni << 4) + (l & 15)) * 64 + k0]);
#pragma unroll
      for (int mi = 0; mi < 4; ++mi)
#pragma unroll
        for (int ni = 0; ni < 4; ++ni)
          acc[mi][ni] = mfma16(af[mi], bfr[ni], acc[mi][ni]);
    }
    __syncthreads();
  }

  if (z < 2) {
    float* dst = (z == 0) ? qproj : kproj;
#pragma unroll
    for (int mi = 0; mi < 4; ++mi)
#pragma unroll
      for (int ni = 0; ni < 4; ++ni)
#pragma unroll
        for (int r = 0; r < 4; ++r) {
          int rowg = brow + (wr << 6) + (mi << 4) + ((l >> 4) << 2) + r;
          int colg = bcol + (wc << 6) + (ni << 4) + (l & 15);
          dst[(size_t)rowg * 1024 + colg] = acc[mi][ni][r];
        }
  } else {
    const int bb = brow >> 11;
    const int nblk = brow & 2047;
#pragma unroll
    for (int mi = 0; mi < 4; ++mi)
#pragma unroll
      for (int ni = 0; ni < 4; ++ni) {
        int n0 = nblk + (wr << 6) + (mi << 4) + ((l >> 4) << 2);
        int colg = bcol + (wc << 6) + (ni << 4) + (l & 15);
        int h = colg >> 6, d = colg & 63;
        ushort4 u;
        u.x = f2bf(acc[mi][ni][0]); u.y = f2bf(acc[mi][ni][1]);
        u.z = f2bf(acc[mi][ni][2]); u.w = f2bf(acc[mi][ni][3]);
        *reinterpret_cast<ushort4*>(
            &vtb[((size_t)(bb * 16 + h) * 64 + d) * 2048 + n0]) = u;
      }
  }
}

// ---------------------------------------------------------------------------
// Per-head LayerNorm (D=64).  DO_SCALE folds mup 0.125 AND log2(e) so the
// attention softmax runs in exp2 domain.
// ---------------------------------------------------------------------------
template <int DO_SCALE>
__global__ __launch_bounds__(256, 4)
void ln_head(const float* __restrict__ in, unsigned short* __restrict__ out,
             const float* __restrict__ gw, const float* __restrict__ bw)
{
  const int tid = threadIdx.x;
  const int w = tid >> 6, l = tid & 63;
  const int row = blockIdx.x * 4 + w;
  const int h = l >> 2, dq = l & 3;
  const float* src = in + (size_t)row * 1024 + h * 64 + dq * 16;
  const float4* p = reinterpret_cast<const float4*>(src);
  float4 a = p[0], b = p[1], c = p[2], d = p[3];
  float x[16] = {a.x, a.y, a.z, a.w, b.x, b.y, b.z, b.w,
                 c.x, c.y, c.z, c.w, d.x, d.y, d.z, d.w};
  float s = 0.f, s2 = 0.f;
#pragma unroll
  for (int j = 0; j < 16; ++j) { s += x[j]; s2 += x[j] * x[j]; }
  s  += __shfl_xor(s, 1);  s  += __shfl_xor(s, 2);
  s2 += __shfl_xor(s2, 1); s2 += __shfl_xor(s2, 2);
  float mean = s * (1.f / 64.f);
  float var  = s2 * (1.f / 64.f) - mean * mean;
  float rstd = rsqrtf(var + 1e-5f);
  float y[16];
#pragma unroll
  for (int j = 0; j < 16; ++j) {
    float t = (x[j] - mean) * rstd * gw[dq * 16 + j] + bw[dq * 16 + j];
    if (DO_SCALE) t *= 0.125f * 1.4426950408889634f;  // mup scale * log2(e)
    y[j] = t;
  }
  int bb = row >> 11, n = row & 2047;
  unsigned short* dst = out + (((size_t)(bb * 16 + h) << 11) + n) * 64 + dq * 16;
  int4 o0, o1;
  o0.x = pk2(y[0], y[1]);  o0.y = pk2(y[2], y[3]);
  o0.z = pk2(y[4], y[5]);  o0.w = pk2(y[6], y[7]);
  o1.x = pk2(y[8], y[9]);  o1.y = pk2(y[10], y[11]);
  o1.z = pk2(y[12], y[13]); o1.w = pk2(y[14], y[15]);
  *reinterpret_cast<int4*>(dst) = o0;
  *reinterpret_cast<int4*>(dst + 8) = o1;
}

// ---------------------------------------------------------------------------
// Flash attention, swapped-QK^T 32x32 structure, exp2-domain softmax,
// cvt_pk+permlane32_swap P-repack, T14 async-STAGE prefetch.
// ---------------------------------------------------------------------------
__global__ __launch_bounds__(256, 2)
void attn_fwd(const unsigned short* __restrict__ Q,
              const unsigned short* __restrict__ K,
              const unsigned short* __restrict__ Vt,
              unsigned short* __restrict__ O)
{
  __shared__ short Ks[64 * 64];
  __shared__ short Vs[64 * 64];
  const int tid = threadIdx.x, w = tid >> 6, l = tid & 63;
  const int lo5 = l & 31, hi = l >> 5;
  const int bh = blockIdx.y;
  const int qbase = blockIdx.x * 128 + w * 32;
  const unsigned short* Qg = Q + ((size_t)bh * 2048 + qbase) * 64;
  const unsigned short* Kg = K + (size_t)bh * 2048 * 64;
  const unsigned short* Vg = Vt + (size_t)bh * 64 * 2048;

  bf16x8 qf[4];
#pragma unroll
  for (int ks = 0; ks < 4; ++ks)
    qf[ks] = *reinterpret_cast<const bf16x8*>(Qg + lo5 * 64 + ks * 16 + hi * 8);

  f32x16 oc0 = zero16(), oc1 = zero16();
  float m = -1e30f, lsum = 0.f;

  auto loadt = [&](int it, int4 kr[2], int4 vr[2]) {
#pragma unroll
    for (int i = 0; i < 2; ++i) {
      int cc = i * 256 + tid, row = cc >> 3, c8 = cc & 7;
      kr[i] = *reinterpret_cast<const int4*>(Kg + (it * 64 + row) * 64 + c8 * 8);
      vr[i] = *reinterpret_cast<const int4*>(Vg + (size_t)row * 2048 + it * 64 + c8 * 8);
    }
  };
  auto storet = [&](const int4 kr[2], const int4 vr[2]) {
#pragma unroll
    for (int i = 0; i < 2; ++i) {
      int cc = i * 256 + tid, row = cc >> 3, c8 = cc & 7;
      *reinterpret_cast<int4*>(&Ks[(row << 6) + ((c8 << 3) ^ ((row & 7) << 3))]) = kr[i];
      *reinterpret_cast<int4*>(&Vs[(row << 6) + ((c8 << 3) ^ ((row & 7) << 3))]) = vr[i];
    }
  };

  {
    int4 kr[2], vr[2];
    loadt(0, kr, vr);
    storet(kr, vr);
  }
  __syncthreads();

  for (int it = 0; it < 32; ++it) {
    int4 kn[2], vn[2];
    if (it < 31) loadt(it + 1, kn, vn);   // issue early; latency hides under compute

    // QK^T (swapped): s = mfma(A=K, B=Q) -> S[q=col][j=row], log2-domain
    f32x16 s0 = zero16(), s1 = zero16();
#pragma unroll
    for (int ks = 0; ks < 4; ++ks) {
      const int colc = (16 * ks + 8 * hi) ^ ((lo5 & 7) << 3);
      bf16x8 k0 = *reinterpret_cast<const bf16x8*>(&Ks[(lo5 << 6) + colc]);
      s0 = mfma32(k0, qf[ks], s0);
      bf16x8 k1 = *reinterpret_cast<const bf16x8*>(&Ks[((32 + lo5) << 6) + colc]);
      s1 = mfma32(k1, qf[ks], s1);
    }

    // online softmax in log2 domain; tree max
    float t[16];
#pragma unroll
    for (int r = 0; r < 16; ++r) t[r] = fmaxf(s0[r], s1[r]);
#pragma unroll
    for (int off = 8; off > 0; off >>= 1)
#pragma unroll
      for (int r = 0; r < off; ++r) t[r] = fmaxf(t[r], t[r + off]);
    float pm = fmaxf(t[0], __shfl_xor(t[0], 32));
    if (!__all(pm <= m + 11.5f)) {   // defer-max (T13), 11.5 = 8*log2e
      float mn = fmaxf(m, pm);
      float al = exp2f(m - mn);
      m = mn; lsum *= al;
#pragma unroll
      for (int r = 0; r < 16; ++r) {
        float ar = __shfl(al, (r & 3) + 8 * (r >> 2) + 4 * hi);
        oc0[r] *= ar; oc1[r] *= ar;
      }
    }

    // exp2 + cvt_pk + permlane repack + PV, per 32-j subchunk
    auto pvsub = [&](const f32x16& sv, int jbase) {
      float p0[16];
#pragma unroll
      for (int r = 0; r < 16; ++r) p0[r] = exp2f(sv[r] - m);
      lsum += (((p0[0] + p0[1]) + (p0[2] + p0[3])) +
               ((p0[4] + p0[5]) + (p0[6] + p0[7]))) +
              (((p0[8] + p0[9]) + (p0[10] + p0[11])) +
               ((p0[12] + p0[13]) + (p0[14] + p0[15])));
#pragma unroll
      for (int f = 0; f < 2; ++f) {
        unsigned x  = cvtpk(p0[8 * f + 0], p0[8 * f + 1]);
        unsigned zz = cvtpk(p0[8 * f + 2], p0[8 * f + 3]);
        unsigned y  = cvtpk(p0[8 * f + 4], p0[8 * f + 5]);
        unsigned ww = cvtpk(p0[8 * f + 6], p0[8 * f + 7]);
        pl32swap(x, y);    // x -> a0, y -> a2
        pl32swap(zz, ww);  // zz -> a1, ww -> a3
        bf16x8 pa = mk8(x, zz, y, ww);
        const int colc = (jbase + 16 * f + 8 * hi);
        bf16x8 v0 = *reinterpret_cast<const bf16x8*>(
            &Vs[(lo5 << 6) + (colc ^ ((lo5 & 7) << 3))]);
        oc0 = mfma32(pa, v0, oc0);
        bf16x8 v1 = *reinterpret_cast<const bf16x8*>(
            &Vs[((32 + lo5) << 6) + (colc ^ ((lo5 & 7) << 3))]);
        oc1 = mfma32(pa, v1, oc1);
      }
    };
    pvsub(s0, 0);
    pvsub(s1, 32);

    __syncthreads();                   // all waves done reading Ks/Vs
    if (it < 31) storet(kn, vn);       // vmcnt drain + LDS write (T14 late half)
    __syncthreads();
  }

  lsum += __shfl_xor(lsum, 32);
  float inv = 1.f / lsum;
  unsigned short* Og = O + ((size_t)(bh >> 4) * 2048 + qbase) * 1024 + (bh & 15) * 64;
#pragma unroll
  for (int r = 0; r < 16; ++r) {
    int qrow = (r & 3) + 8 * (r >> 2) + 4 * hi;
    float ir = __shfl(inv, qrow);
    Og[qrow * 1024 + lo5]      = f2bf(oc0[r] * ir);
    Og[qrow * 1024 + 32 + lo5] = f2bf(oc1[r] * ir);
  }
}

// ---------------------------------------------------------------------------
// Output projection (m97 structure): out = Ocat @ Wp^T + bp, fp32 out.
// ---------------------------------------------------------------------------
__global__ __launch_bounds__(256, 2)
void gemm_out_bf(const unsigned short* __restrict__ ob,
                 const unsigned short* __restrict__ wpb,
                 const float* __restrict__ bp, float* __restrict__ out)
{
  __shared__ short As[128 * 64];
  __shared__ short Bs[128 * 64];
  const int tid = threadIdx.x;
  const int l = tid & 63, w = tid >> 6;
  const int wr = w >> 1, wc = w & 1;
  const int brow = blockIdx.y * 128, bcol = blockIdx.x * 128;

  const f32x4 zero = {0.f, 0.f, 0.f, 0.f};
  f32x4 acc[4][4];
#pragma unroll
  for (int mi = 0; mi < 4; ++mi)
#pragma unroll
    for (int ni = 0; ni < 4; ++ni) acc[mi][ni] = zero;

  const int srow = w * 32 + (l >> 3);
  const int scol = (l & 7) * 8;

  for (int kt = 0; kt < 16; ++kt) {
    const unsigned short* ga = ob + (size_t)(brow + srow) * 1024 + kt * 64 + scol;
    const unsigned short* gb = wpb + (size_t)(bcol + srow) * 1024 + kt * 64 + scol;
#pragma unroll
    for (int i = 0; i < 4; ++i) {
      gl16(ga + (size_t)i * 8 * 1024, &As[(w * 32 + i * 8) * 64]);
      gl16(gb + (size_t)i * 8 * 1024, &Bs[(w * 32 + i * 8) * 64]);
    }
    __syncthreads();
#pragma unroll
    for (int kk = 0; kk < 2; ++kk) {
      const int k0 = kk * 32 + ((l >> 4) << 3);
      bf16x8 af[4], bfr[4];
#pragma unroll
      for (int mi = 0; mi < 4; ++mi)
        af[mi] = *reinterpret_cast<const bf16x8*>(
            &As[((wr << 6) + (mi << 4) + (l & 15)) * 64 + k0]);
#pragma unroll
      for (int ni = 0; ni < 4; ++ni)
        bfr[ni] = *reinterpret_cast<const bf16x8*>(
            &Bs[((wc << 6) + (ni << 4) + (l & 15)) * 64 + k0]);
#pragma unroll
      for (int mi = 0; mi < 4; ++mi)
#pragma unroll
        for (int ni = 0; ni < 4; ++ni)
          acc[mi][ni] = mfma16(af[mi], bfr[ni], acc[mi][ni]);
    }
    __syncthreads();
  }

  float bias[4];
#pragma unroll
  for (int ni = 0; ni < 4; ++ni)
    bias[ni] = bp[bcol + (wc << 6) + (ni << 4) + (l & 15)];
#pragma unroll
  for (int mi = 0; mi < 4; ++mi)
#pragma unroll
    for (int ni = 0; ni < 4; ++ni)
#pragma unroll
      for (int r = 0; r < 4; ++r) {
        int rowg = brow + (wr << 6) + (mi << 4) + ((l >> 4) << 2) + r;
        int colg = bcol + (wc << 6) + (ni << 4) + (l & 15);
        out[(size_t)rowg * 1024 + colg] = acc[mi][ni][r] + bias[ni];
      }
}

// ---------------------------------------------------------------------------
extern "C" void kernel_launch(void* const* d_in, const int* in_sizes, int n_in,
                              void* d_out, int out_size, void* d_ws, size_t ws_size,
                              hipStream_t stream)
{
  const float* x1 = (const float*)d_in[0];
  const float* x2 = (const float*)d_in[1];
  const float* Wq = (const float*)d_in[2];
  const float* Wk = (const float*)d_in[3];
  const float* Wv = (const float*)d_in[4];
  const float* Wp = (const float*)d_in[5];
  const float* bp = (const float*)d_in[6];
  const float* lg = (const float*)d_in[7];
  const float* lb = (const float*)d_in[8];

  char* wsb = (char*)d_ws;
  unsigned short* xb   = (unsigned short*)wsb;             // 24 MiB (12M ushort)
  float* qproj = (float*)(wsb + 25165824);                 // 16 MiB
  float* kproj = (float*)(wsb + 41943040);                 // 16 MiB
  unsigned short* qb   = (unsigned short*)(wsb + 58720256);// 8 MiB
  unsigned short* kb   = qb + 4194304;                     // 8 MiB
  unsigned short* vtb  = kb + 4194304;                     // 8 MiB (V^T)
  unsigned short* obuf = vtb + 4194304;                    // 8 MiB
  float* out = (float*)d_out;

  conv_bf16<<<6144, 256, 0, stream>>>(x1, x2, Wq, Wk, Wv, Wp, xb);
  gemm_qkv_bf<<<dim3(8, 32, 3), 256, 0, stream>>>(xb, qproj, kproj, vtb);
  ln_head<1><<<1024, 256, 0, stream>>>(qproj, qb, lg, lb);
  ln_head<0><<<1024, 256, 0, stream>>>(kproj, kb, lg, lb);
  attn_fwd<<<dim3(16, 32), 256, 0, stream>>>(qb, kb, vtb, obuf);
  gemm_out_bf<<<dim3(8, 32), 256, 0, stream>>>(obuf,
      xb + 11534336, bp, out);
}

// Round 5
// 156.628 us; speedup vs baseline: 1.1907x; 1.1907x over previous
//
#include <hip/hip_runtime.h>

#define DEV static __device__ __forceinline__

using bf16x8 = __attribute__((ext_vector_type(8))) short;
using f32x4  = __attribute__((ext_vector_type(4))) float;
using f32x16 = __attribute__((ext_vector_type(16))) float;

DEV unsigned short f2bf(float f) {
  union { float f; unsigned u; } v; v.f = f;
  return (unsigned short)((v.u + 0x7fffu + ((v.u >> 16) & 1u)) >> 16);
}
DEV unsigned pk2(float lo, float hi) {
  return (unsigned)f2bf(lo) | ((unsigned)f2bf(hi) << 16);
}
// single-instruction packed fp32->bf16 (RNE)
DEV unsigned cvtpk(float lo, float hi) {
  unsigned r;
  asm("v_cvt_pk_bf16_f32 %0, %1, %2" : "=v"(r) : "v"(lo), "v"(hi));
  return r;
}
// swap: a_new=[a_lo,b_lo], b_new=[a_hi,b_hi] across lane halves
DEV void pl32swap(unsigned &a, unsigned &b) {
  asm("v_permlane32_swap_b32 %0, %1" : "+v"(a), "+v"(b));
}
DEV bf16x8 mk8(unsigned a, unsigned b, unsigned c, unsigned d) {
  union { unsigned u[4]; bf16x8 v; } t;
  t.u[0] = a; t.u[1] = b; t.u[2] = c; t.u[3] = d;
  return t.v;
}
DEV f32x4 mfma16(bf16x8 a, bf16x8 b, f32x4 c) {
  return __builtin_amdgcn_mfma_f32_16x16x32_bf16(a, b, c, 0, 0, 0);
}
DEV f32x16 mfma32(bf16x8 a, bf16x8 b, f32x16 c) {
  return __builtin_amdgcn_mfma_f32_32x32x16_bf16(a, b, c, 0, 0, 0);
}
DEV f32x16 zero16() {
  f32x16 z;
#pragma unroll
  for (int i = 0; i < 16; ++i) z[i] = 0.f;
  return z;
}

typedef const __attribute__((address_space(1))) unsigned int* gas1;
typedef __attribute__((address_space(3))) unsigned int* las3;
DEV void gl16(const void* g, void* l) {
  __builtin_amdgcn_global_load_lds((gas1)g, (las3)l, 16, 0, 0);
}

// ---------------------------------------------------------------------------
// fp32 -> bf16 pre-convert: x1(4M) x2(4M) Wq Wk Wv Wp (1M each) -> 12M ushort.
// ---------------------------------------------------------------------------
__global__ __launch_bounds__(256, 8)
void conv_bf16(const float* __restrict__ x1, const float* __restrict__ x2,
               const float* __restrict__ Wq, const float* __restrict__ Wk,
               const float* __restrict__ Wv, const float* __restrict__ Wp,
               unsigned short* __restrict__ o)
{
  size_t e = ((size_t)blockIdx.x * 256 + threadIdx.x) * 8;
  const float* s; size_t off;
  if (e < 4194304u)       { s = x1; off = e; }
  else if (e < 8388608u)  { s = x2; off = e - 4194304u; }
  else if (e < 9437184u)  { s = Wq; off = e - 8388608u; }
  else if (e < 10485760u) { s = Wk; off = e - 9437184u; }
  else if (e < 11534336u) { s = Wv; off = e - 10485760u; }
  else                    { s = Wp; off = e - 11534336u; }
  const float4* p = reinterpret_cast<const float4*>(s + off);
  float4 a = p[0], b = p[1];
  int4 r;
  r.x = pk2(a.x, a.y); r.y = pk2(a.z, a.w);
  r.z = pk2(b.x, b.y); r.w = pk2(b.z, b.w);
  *reinterpret_cast<int4*>(o + e) = r;
}

// ---------------------------------------------------------------------------
// Fused QKV GEMM (m97 structure), bf16 in.
// z=0 -> qproj fp32; z=1 -> kproj fp32; z=2 -> V^T bf16 [B,H,D,M].
// ---------------------------------------------------------------------------
__global__ __launch_bounds__(256, 2)
void gemm_qkv_bf(const unsigned short* __restrict__ xb,
                 float* __restrict__ qproj, float* __restrict__ kproj,
                 unsigned short* __restrict__ vtb)
{
  __shared__ short As[128 * 64];
  __shared__ short Bs[128 * 64];
  const int tid = threadIdx.x;
  const int l = tid & 63, w = tid >> 6;
  const int wr = w >> 1, wc = w & 1;
  const int z = blockIdx.z;
  const unsigned short* A = (z == 0) ? xb : (xb + 4194304);
  const unsigned short* W = xb + 8388608 + (size_t)z * 1048576;
  const int brow = blockIdx.y * 128, bcol = blockIdx.x * 128;

  const f32x4 zero = {0.f, 0.f, 0.f, 0.f};
  f32x4 acc[4][4];
#pragma unroll
  for (int mi = 0; mi < 4; ++mi)
#pragma unroll
    for (int ni = 0; ni < 4; ++ni) acc[mi][ni] = zero;

  const int srow = w * 32 + (l >> 3);
  const int scol = (l & 7) * 8;

  for (int kt = 0; kt < 16; ++kt) {
    const unsigned short* ga = A + (size_t)(brow + srow) * 1024 + kt * 64 + scol;
    const unsigned short* gb = W + (size_t)(bcol + srow) * 1024 + kt * 64 + scol;
#pragma unroll
    for (int i = 0; i < 4; ++i) {
      gl16(ga + (size_t)i * 8 * 1024, &As[(w * 32 + i * 8) * 64]);
      gl16(gb + (size_t)i * 8 * 1024, &Bs[(w * 32 + i * 8) * 64]);
    }
    __syncthreads();
#pragma unroll
    for (int kk = 0; kk < 2; ++kk) {
      const int k0 = kk * 32 + ((l >> 4) << 3);
      bf16x8 af[4], bfr[4];
#pragma unroll
      for (int mi = 0; mi < 4; ++mi)
        af[mi] = *reinterpret_cast<const bf16x8*>(
            &As[((wr << 6) + (mi << 4) + (l & 15)) * 64 + k0]);
#pragma unroll
      for (int ni = 0; ni < 4; ++ni)
        bfr[ni] = *reinterpret_cast<const bf16x8*>(
            &Bs[((wc << 6) + (ni << 4) + (l & 15)) * 64 + k0]);
#pragma unroll
      for (int mi = 0; mi < 4; ++mi)
#pragma unroll
        for (int ni = 0; ni < 4; ++ni)
          acc[mi][ni] = mfma16(af[mi], bfr[ni], acc[mi][ni]);
    }
    __syncthreads();
  }

  if (z < 2) {
    float* dst = (z == 0) ? qproj : kproj;
#pragma unroll
    for (int mi = 0; mi < 4; ++mi)
#pragma unroll
      for (int ni = 0; ni < 4; ++ni)
#pragma unroll
        for (int r = 0; r < 4; ++r) {
          int rowg = brow + (wr << 6) + (mi << 4) + ((l >> 4) << 2) + r;
          int colg = bcol + (wc << 6) + (ni << 4) + (l & 15);
          dst[(size_t)rowg * 1024 + colg] = acc[mi][ni][r];
        }
  } else {
    const int bb = brow >> 11;
    const int nblk = brow & 2047;
#pragma unroll
    for (int mi = 0; mi < 4; ++mi)
#pragma unroll
      for (int ni = 0; ni < 4; ++ni) {
        int n0 = nblk + (wr << 6) + (mi << 4) + ((l >> 4) << 2);
        int colg = bcol + (wc << 6) + (ni << 4) + (l & 15);
        int h = colg >> 6, d = colg & 63;
        ushort4 u;
        u.x = f2bf(acc[mi][ni][0]); u.y = f2bf(acc[mi][ni][1]);
        u.z = f2bf(acc[mi][ni][2]); u.w = f2bf(acc[mi][ni][3]);
        *reinterpret_cast<ushort4*>(
            &vtb[((size_t)(bb * 16 + h) * 64 + d) * 2048 + n0]) = u;
      }
  }
}

// ---------------------------------------------------------------------------
// Per-head LayerNorm (D=64).  DO_SCALE folds mup 0.125 AND log2(e) so the
// attention softmax runs in exp2 domain.
// ---------------------------------------------------------------------------
template <int DO_SCALE>
__global__ __launch_bounds__(256, 4)
void ln_head(const float* __restrict__ in, unsigned short* __restrict__ out,
             const float* __restrict__ gw, const float* __restrict__ bw)
{
  const int tid = threadIdx.x;
  const int w = tid >> 6, l = tid & 63;
  const int row = blockIdx.x * 4 + w;
  const int h = l >> 2, dq = l & 3;
  const float* src = in + (size_t)row * 1024 + h * 64 + dq * 16;
  const float4* p = reinterpret_cast<const float4*>(src);
  float4 a = p[0], b = p[1], c = p[2], d = p[3];
  float x[16] = {a.x, a.y, a.z, a.w, b.x, b.y, b.z, b.w,
                 c.x, c.y, c.z, c.w, d.x, d.y, d.z, d.w};
  float s = 0.f, s2 = 0.f;
#pragma unroll
  for (int j = 0; j < 16; ++j) { s += x[j]; s2 += x[j] * x[j]; }
  s  += __shfl_xor(s, 1);  s  += __shfl_xor(s, 2);
  s2 += __shfl_xor(s2, 1); s2 += __shfl_xor(s2, 2);
  float mean = s * (1.f / 64.f);
  float var  = s2 * (1.f / 64.f) - mean * mean;
  float rstd = rsqrtf(var + 1e-5f);
  float y[16];
#pragma unroll
  for (int j = 0; j < 16; ++j) {
    float t = (x[j] - mean) * rstd * gw[dq * 16 + j] + bw[dq * 16 + j];
    if (DO_SCALE) t *= 0.125f * 1.4426950408889634f;  // mup scale * log2(e)
    y[j] = t;
  }
  int bb = row >> 11, n = row & 2047;
  unsigned short* dst = out + (((size_t)(bb * 16 + h) << 11) + n) * 64 + dq * 16;
  int4 o0, o1;
  o0.x = pk2(y[0], y[1]);  o0.y = pk2(y[2], y[3]);
  o0.z = pk2(y[4], y[5]);  o0.w = pk2(y[6], y[7]);
  o1.x = pk2(y[8], y[9]);  o1.y = pk2(y[10], y[11]);
  o1.z = pk2(y[12], y[13]); o1.w = pk2(y[14], y[15]);
  *reinterpret_cast<int4*>(dst) = o0;
  *reinterpret_cast<int4*>(dst + 8) = o1;
}

// ---------------------------------------------------------------------------
// Flash attention, swapped-QK^T 32x32, exp2-domain softmax,
// cvt_pk + permlane32_swap P-repack, LDS double-buffer (1 barrier/iter),
// named-register prefetch (no scratch), setprio around MFMA clusters.
// ---------------------------------------------------------------------------
__global__ __launch_bounds__(256, 2)
void attn_fwd(const unsigned short* __restrict__ Q,
              const unsigned short* __restrict__ K,
              const unsigned short* __restrict__ Vt,
              unsigned short* __restrict__ O)
{
  __shared__ short Ks[2][64 * 64];
  __shared__ short Vs[2][64 * 64];
  const int tid = threadIdx.x, w = tid >> 6, l = tid & 63;
  const int lo5 = l & 31, hi = l >> 5;
  const int bh = blockIdx.y;
  const int qbase = blockIdx.x * 128 + w * 32;
  const unsigned short* Qg = Q + ((size_t)bh * 2048 + qbase) * 64;
  const unsigned short* Kg = K + (size_t)bh * 2048 * 64;
  const unsigned short* Vg = Vt + (size_t)bh * 64 * 2048;

  bf16x8 qf[4];
#pragma unroll
  for (int ks = 0; ks < 4; ++ks)
    qf[ks] = *reinterpret_cast<const bf16x8*>(Qg + lo5 * 64 + ks * 16 + hi * 8);

  f32x16 oc0 = zero16(), oc1 = zero16();
  float m = -1e30f, lsum = 0.f;

  // staging geometry: thread stages rows srow and srow+32 of K tile and of
  // Vt tile (Vt row = d, 64 rows), 16B each.
  const int srow = tid >> 3;            // 0..31
  const int sc8 = (tid & 7) * 8;        // element offset within row
  const int swz0 = sc8 ^ ((srow & 7) * 8);  // same for srow+32

  // named prefetch registers (NO array-pointer lambdas -> stay in VGPRs)
  int4 ka0, ka1, va0, va1;
  ka0 = *reinterpret_cast<const int4*>(Kg + srow * 64 + sc8);
  ka1 = *reinterpret_cast<const int4*>(Kg + (32 + srow) * 64 + sc8);
  va0 = *reinterpret_cast<const int4*>(Vg + (size_t)srow * 2048 + sc8);
  va1 = *reinterpret_cast<const int4*>(Vg + (size_t)(32 + srow) * 2048 + sc8);
  *reinterpret_cast<int4*>(&Ks[0][(srow << 6) + swz0]) = ka0;
  *reinterpret_cast<int4*>(&Ks[0][((32 + srow) << 6) + swz0]) = ka1;
  *reinterpret_cast<int4*>(&Vs[0][(srow << 6) + swz0]) = va0;
  *reinterpret_cast<int4*>(&Vs[0][((32 + srow) << 6) + swz0]) = va1;
  __syncthreads();

  for (int it = 0; it < 32; ++it) {
    const int cur = it & 1;
    const short* Kc = Ks[cur];
    const short* Vc = Vs[cur];

    if (it < 31) {   // issue next-tile loads; latency hides under compute
      const unsigned short* kg = Kg + (it + 1) * 64 * 64;
      const unsigned short* vg = Vg + (it + 1) * 64;
      ka0 = *reinterpret_cast<const int4*>(kg + srow * 64 + sc8);
      ka1 = *reinterpret_cast<const int4*>(kg + (32 + srow) * 64 + sc8);
      va0 = *reinterpret_cast<const int4*>(vg + (size_t)srow * 2048 + sc8);
      va1 = *reinterpret_cast<const int4*>(vg + (size_t)(32 + srow) * 2048 + sc8);
    }

    // QK^T (swapped): s = mfma(A=K, B=Q) -> S[q=col][j=row], log2 domain
    f32x16 s0 = zero16(), s1 = zero16();
    __builtin_amdgcn_s_setprio(1);
#pragma unroll
    for (int ks = 0; ks < 4; ++ks) {
      const int colc = (16 * ks + 8 * hi) ^ ((lo5 & 7) << 3);
      bf16x8 k0 = *reinterpret_cast<const bf16x8*>(&Kc[(lo5 << 6) + colc]);
      s0 = mfma32(k0, qf[ks], s0);
      bf16x8 k1 = *reinterpret_cast<const bf16x8*>(&Kc[((32 + lo5) << 6) + colc]);
      s1 = mfma32(k1, qf[ks], s1);
    }
    __builtin_amdgcn_s_setprio(0);

    // online softmax (log2 domain), tree max
    float t[16];
#pragma unroll
    for (int r = 0; r < 16; ++r) t[r] = fmaxf(s0[r], s1[r]);
#pragma unroll
    for (int off = 8; off > 0; off >>= 1)
#pragma unroll
      for (int r = 0; r < off; ++r) t[r] = fmaxf(t[r], t[r + off]);
    float pm = fmaxf(t[0], __shfl_xor(t[0], 32));
    if (!__all(pm <= m + 11.5f)) {   // defer-max (T13), 11.5 = 8*log2e
      float mn = fmaxf(m, pm);
      float al = exp2f(m - mn);
      m = mn; lsum *= al;
#pragma unroll
      for (int r = 0; r < 16; ++r) {
        float ar = __shfl(al, (r & 3) + 8 * (r >> 2) + 4 * hi);
        oc0[r] *= ar; oc1[r] *= ar;
      }
    }

    // exp2 + cvt_pk + permlane repack + PV, per 32-j subchunk
    auto pvsub = [&](const f32x16& sv, int jbase) {
      float p0[16];
#pragma unroll
      for (int r = 0; r < 16; ++r) p0[r] = exp2f(sv[r] - m);
      lsum += (((p0[0] + p0[1]) + (p0[2] + p0[3])) +
               ((p0[4] + p0[5]) + (p0[6] + p0[7]))) +
              (((p0[8] + p0[9]) + (p0[10] + p0[11])) +
               ((p0[12] + p0[13]) + (p0[14] + p0[15])));
#pragma unroll
      for (int f = 0; f < 2; ++f) {
        unsigned x  = cvtpk(p0[8 * f + 0], p0[8 * f + 1]);
        unsigned zz = cvtpk(p0[8 * f + 2], p0[8 * f + 3]);
        unsigned y  = cvtpk(p0[8 * f + 4], p0[8 * f + 5]);
        unsigned ww = cvtpk(p0[8 * f + 6], p0[8 * f + 7]);
        pl32swap(x, y);
        pl32swap(zz, ww);
        bf16x8 pa = mk8(x, zz, y, ww);
        const int colc = (jbase + 16 * f + 8 * hi);
        bf16x8 v0 = *reinterpret_cast<const bf16x8*>(
            &Vc[(lo5 << 6) + (colc ^ ((lo5 & 7) << 3))]);
        bf16x8 v1 = *reinterpret_cast<const bf16x8*>(
            &Vc[((32 + lo5) << 6) + (colc ^ ((lo5 & 7) << 3))]);
        __builtin_amdgcn_s_setprio(1);
        oc0 = mfma32(pa, v0, oc0);
        oc1 = mfma32(pa, v1, oc1);
        __builtin_amdgcn_s_setprio(0);
      }
    };
    pvsub(s0, 0);
    pvsub(s1, 32);

    if (it < 31) {   // write next tile into the other buffer (no hazard)
      const int nb = cur ^ 1;
      *reinterpret_cast<int4*>(&Ks[nb][(srow << 6) + swz0]) = ka0;
      *reinterpret_cast<int4*>(&Ks[nb][((32 + srow) << 6) + swz0]) = ka1;
      *reinterpret_cast<int4*>(&Vs[nb][(srow << 6) + swz0]) = va0;
      *reinterpret_cast<int4*>(&Vs[nb][((32 + srow) << 6) + swz0]) = va1;
    }
    __syncthreads();   // single barrier: covers buffer swap both ways
  }

  lsum += __shfl_xor(lsum, 32);
  float inv = 1.f / lsum;
  unsigned short* Og = O + ((size_t)(bh >> 4) * 2048 + qbase) * 1024 + (bh & 15) * 64;
#pragma unroll
  for (int r = 0; r < 16; ++r) {
    int qrow = (r & 3) + 8 * (r >> 2) + 4 * hi;
    float ir = __shfl(inv, qrow);
    Og[qrow * 1024 + lo5]      = f2bf(oc0[r] * ir);
    Og[qrow * 1024 + 32 + lo5] = f2bf(oc1[r] * ir);
  }
}

// ---------------------------------------------------------------------------
// Output projection (m97 structure): out = Ocat @ Wp^T + bp, fp32 out.
// ---------------------------------------------------------------------------
__global__ __launch_bounds__(256, 2)
void gemm_out_bf(const unsigned short* __restrict__ ob,
                 const unsigned short* __restrict__ wpb,
                 const float* __restrict__ bp, float* __restrict__ out)
{
  __shared__ short As[128 * 64];
  __shared__ short Bs[128 * 64];
  const int tid = threadIdx.x;
  const int l = tid & 63, w = tid >> 6;
  const int wr = w >> 1, wc = w & 1;
  const int brow = blockIdx.y * 128, bcol = blockIdx.x * 128;

  const f32x4 zero = {0.f, 0.f, 0.f, 0.f};
  f32x4 acc[4][4];
#pragma unroll
  for (int mi = 0; mi < 4; ++mi)
#pragma unroll
    for (int ni = 0; ni < 4; ++ni) acc[mi][ni] = zero;

  const int srow = w * 32 + (l >> 3);
  const int scol = (l & 7) * 8;

  for (int kt = 0; kt < 16; ++kt) {
    const unsigned short* ga = ob + (size_t)(brow + srow) * 1024 + kt * 64 + scol;
    const unsigned short* gb = wpb + (size_t)(bcol + srow) * 1024 + kt * 64 + scol;
#pragma unroll
    for (int i = 0; i < 4; ++i) {
      gl16(ga + (size_t)i * 8 * 1024, &As[(w * 32 + i * 8) * 64]);
      gl16(gb + (size_t)i * 8 * 1024, &Bs[(w * 32 + i * 8) * 64]);
    }
    __syncthreads();
#pragma unroll
    for (int kk = 0; kk < 2; ++kk) {
      const int k0 = kk * 32 + ((l >> 4) << 3);
      bf16x8 af[4], bfr[4];
#pragma unroll
      for (int mi = 0; mi < 4; ++mi)
        af[mi] = *reinterpret_cast<const bf16x8*>(
            &As[((wr << 6) + (mi << 4) + (l & 15)) * 64 + k0]);
#pragma unroll
      for (int ni = 0; ni < 4; ++ni)
        bfr[ni] = *reinterpret_cast<const bf16x8*>(
            &Bs[((wc << 6) + (ni << 4) + (l & 15)) * 64 + k0]);
#pragma unroll
      for (int mi = 0; mi < 4; ++mi)
#pragma unroll
        for (int ni = 0; ni < 4; ++ni)
          acc[mi][ni] = mfma16(af[mi], bfr[ni], acc[mi][ni]);
    }
    __syncthreads();
  }

  float bias[4];
#pragma unroll
  for (int ni = 0; ni < 4; ++ni)
    bias[ni] = bp[bcol + (wc << 6) + (ni << 4) + (l & 15)];
#pragma unroll
  for (int mi = 0; mi < 4; ++mi)
#pragma unroll
    for (int ni = 0; ni < 4; ++ni)
#pragma unroll
      for (int r = 0; r < 4; ++r) {
        int rowg = brow + (wr << 6) + (mi << 4) + ((l >> 4) << 2) + r;
        int colg = bcol + (wc << 6) + (ni << 4) + (l & 15);
        out[(size_t)rowg * 1024 + colg] = acc[mi][ni][r] + bias[ni];
      }
}

// ---------------------------------------------------------------------------
extern "C" void kernel_launch(void* const* d_in, const int* in_sizes, int n_in,
                              void* d_out, int out_size, void* d_ws, size_t ws_size,
                              hipStream_t stream)
{
  const float* x1 = (const float*)d_in[0];
  const float* x2 = (const float*)d_in[1];
  const float* Wq = (const float*)d_in[2];
  const float* Wk = (const float*)d_in[3];
  const float* Wv = (const float*)d_in[4];
  const float* Wp = (const float*)d_in[5];
  const float* bp = (const float*)d_in[6];
  const float* lg = (const float*)d_in[7];
  const float* lb = (const float*)d_in[8];

  char* wsb = (char*)d_ws;
  unsigned short* xb   = (unsigned short*)wsb;             // 24 MiB (12M ushort)
  float* qproj = (float*)(wsb + 25165824);                 // 16 MiB
  float* kproj = (float*)(wsb + 41943040);                 // 16 MiB
  unsigned short* qb   = (unsigned short*)(wsb + 58720256);// 8 MiB
  unsigned short* kb   = qb + 4194304;                     // 8 MiB
  unsigned short* vtb  = kb + 4194304;                     // 8 MiB (V^T)
  unsigned short* obuf = vtb + 4194304;                    // 8 MiB
  float* out = (float*)d_out;

  conv_bf16<<<6144, 256, 0, stream>>>(x1, x2, Wq, Wk, Wv, Wp, xb);
  gemm_qkv_bf<<<dim3(8, 32, 3), 256, 0, stream>>>(xb, qproj, kproj, vtb);
  ln_head<1><<<1024, 256, 0, stream>>>(qproj, qb, lg, lb);
  ln_head<0><<<1024, 256, 0, stream>>>(kproj, kb, lg, lb);
  attn_fwd<<<dim3(16, 32), 256, 0, stream>>>(qb, kb, vtb, obuf);
  gemm_out_bf<<<dim3(8, 32), 256, 0, stream>>>(obuf,
      xb + 11534336, bp, out);
}

// Round 6
// 134.437 us; speedup vs baseline: 1.3872x; 1.1651x over previous
//
#include <hip/hip_runtime.h>

#define DEV static __device__ __forceinline__

using bf16x8 = __attribute__((ext_vector_type(8))) short;
using f32x4  = __attribute__((ext_vector_type(4))) float;
using f32x16 = __attribute__((ext_vector_type(16))) float;

DEV unsigned short f2bf(float f) {
  union { float f; unsigned u; } v; v.f = f;
  return (unsigned short)((v.u + 0x7fffu + ((v.u >> 16) & 1u)) >> 16);
}
DEV unsigned pk2(float lo, float hi) {
  return (unsigned)f2bf(lo) | ((unsigned)f2bf(hi) << 16);
}
// single-instruction packed fp32->bf16 (RNE)
DEV unsigned cvtpk(float lo, float hi) {
  unsigned r;
  asm("v_cvt_pk_bf16_f32 %0, %1, %2" : "=v"(r) : "v"(lo), "v"(hi));
  return r;
}
// swap: a_new=[a_lo,b_lo], b_new=[a_hi,b_hi] across lane halves
DEV void pl32swap(unsigned &a, unsigned &b) {
  asm("v_permlane32_swap_b32 %0, %1" : "+v"(a), "+v"(b));
}
DEV bf16x8 mk8(unsigned a, unsigned b, unsigned c, unsigned d) {
  union { unsigned u[4]; bf16x8 v; } t;
  t.u[0] = a; t.u[1] = b; t.u[2] = c; t.u[3] = d;
  return t.v;
}
DEV f32x4 mfma16(bf16x8 a, bf16x8 b, f32x4 c) {
  return __builtin_amdgcn_mfma_f32_16x16x32_bf16(a, b, c, 0, 0, 0);
}
DEV f32x16 mfma32(bf16x8 a, bf16x8 b, f32x16 c) {
  return __builtin_amdgcn_mfma_f32_32x32x16_bf16(a, b, c, 0, 0, 0);
}
DEV f32x16 zero16() {
  f32x16 z;
#pragma unroll
  for (int i = 0; i < 16; ++i) z[i] = 0.f;
  return z;
}

typedef const __attribute__((address_space(1))) unsigned int* gas1;
typedef __attribute__((address_space(3))) unsigned int* las3;
DEV void gl16(const void* g, void* l) {
  __builtin_amdgcn_global_load_lds((gas1)g, (las3)l, 16, 0, 0);
}

// ---------------------------------------------------------------------------
// fp32 -> bf16 pre-convert: x1(4M) x2(4M) Wq Wk Wv Wp (1M each) -> 12M ushort.
// ---------------------------------------------------------------------------
__global__ __launch_bounds__(256, 8)
void conv_bf16(const float* __restrict__ x1, const float* __restrict__ x2,
               const float* __restrict__ Wq, const float* __restrict__ Wk,
               const float* __restrict__ Wv, const float* __restrict__ Wp,
               unsigned short* __restrict__ o)
{
  size_t e = ((size_t)blockIdx.x * 256 + threadIdx.x) * 8;
  const float* s; size_t off;
  if (e < 4194304u)       { s = x1; off = e; }
  else if (e < 8388608u)  { s = x2; off = e - 4194304u; }
  else if (e < 9437184u)  { s = Wq; off = e - 8388608u; }
  else if (e < 10485760u) { s = Wk; off = e - 9437184u; }
  else if (e < 11534336u) { s = Wv; off = e - 10485760u; }
  else                    { s = Wp; off = e - 11534336u; }
  const float4* p = reinterpret_cast<const float4*>(s + off);
  float4 a = p[0], b = p[1];
  int4 r;
  r.x = (int)cvtpk(a.x, a.y); r.y = (int)cvtpk(a.z, a.w);
  r.z = (int)cvtpk(b.x, b.y); r.w = (int)cvtpk(b.z, b.w);
  *reinterpret_cast<int4*>(o + e) = r;
}

// ---------------------------------------------------------------------------
// Fused QKV GEMM (m97 structure) + fused per-head LayerNorm epilogue.
// z=0 -> qb bf16 [B,H,N,64], LN'd and scaled by 0.125*log2e
// z=1 -> kb bf16 [B,H,M,64], LN'd
// z=2 -> vtb bf16 [B,H,D,M] (V transposed)
// ---------------------------------------------------------------------------
__global__ __launch_bounds__(256, 2)
void gemm_qkv_bf(const unsigned short* __restrict__ xb,
                 const float* __restrict__ lg, const float* __restrict__ lb,
                 unsigned short* __restrict__ qb, unsigned short* __restrict__ kb,
                 unsigned short* __restrict__ vtb)
{
  __shared__ short As[128 * 64];
  __shared__ short Bs[128 * 64];
  const int tid = threadIdx.x;
  const int l = tid & 63, w = tid >> 6;
  const int wr = w >> 1, wc = w & 1;
  const int z = blockIdx.z;
  const unsigned short* A = (z == 0) ? xb : (xb + 4194304);
  const unsigned short* W = xb + 8388608 + (size_t)z * 1048576;
  const int brow = blockIdx.y * 128, bcol = blockIdx.x * 128;

  const f32x4 zero = {0.f, 0.f, 0.f, 0.f};
  f32x4 acc[4][4];
#pragma unroll
  for (int mi = 0; mi < 4; ++mi)
#pragma unroll
    for (int ni = 0; ni < 4; ++ni) acc[mi][ni] = zero;

  const int srow = w * 32 + (l >> 3);
  const int scol = (l & 7) * 8;

  for (int kt = 0; kt < 16; ++kt) {
    const unsigned short* ga = A + (size_t)(brow + srow) * 1024 + kt * 64 + scol;
    const unsigned short* gb = W + (size_t)(bcol + srow) * 1024 + kt * 64 + scol;
#pragma unroll
    for (int i = 0; i < 4; ++i) {
      gl16(ga + (size_t)i * 8 * 1024, &As[(w * 32 + i * 8) * 64]);
      gl16(gb + (size_t)i * 8 * 1024, &Bs[(w * 32 + i * 8) * 64]);
    }
    __syncthreads();
#pragma unroll
    for (int kk = 0; kk < 2; ++kk) {
      const int k0 = kk * 32 + ((l >> 4) << 3);
      bf16x8 af[4], bfr[4];
#pragma unroll
      for (int mi = 0; mi < 4; ++mi)
        af[mi] = *reinterpret_cast<const bf16x8*>(
            &As[((wr << 6) + (mi << 4) + (l & 15)) * 64 + k0]);
#pragma unroll
      for (int ni = 0; ni < 4; ++ni)
        bfr[ni] = *reinterpret_cast<const bf16x8*>(
            &Bs[((wc << 6) + (ni << 4) + (l & 15)) * 64 + k0]);
#pragma unroll
      for (int mi = 0; mi < 4; ++mi)
#pragma unroll
        for (int ni = 0; ni < 4; ++ni)
          acc[mi][ni] = mfma16(af[mi], bfr[ni], acc[mi][ni]);
    }
    __syncthreads();
  }

  if (z < 2) {
    // fused per-head LayerNorm: this wave's 64 cols == one full head
    unsigned short* dst = (z == 0) ? qb : kb;
    const float scl = (z == 0) ? 0.18033688011112042f : 1.0f; // 0.125*log2(e)
    const int h = blockIdx.x * 2 + wc;
    float gw4[4], bw4[4];
#pragma unroll
    for (int ni = 0; ni < 4; ++ni) {
      gw4[ni] = lg[ni * 16 + (l & 15)] * scl;
      bw4[ni] = lb[ni * 16 + (l & 15)] * scl;
    }
#pragma unroll
    for (int mi = 0; mi < 4; ++mi) {
      float ylo[4];
#pragma unroll
      for (int r = 0; r < 4; ++r) {
        float v0 = acc[mi][0][r], v1 = acc[mi][1][r];
        float v2 = acc[mi][2][r], v3 = acc[mi][3][r];
        float s  = (v0 + v1) + (v2 + v3);
        float s2 = (v0 * v0 + v1 * v1) + (v2 * v2 + v3 * v3);
#pragma unroll
        for (int off = 1; off < 16; off <<= 1) {
          s  += __shfl_xor(s, off);
          s2 += __shfl_xor(s2, off);
        }
        float mean = s * (1.f / 64.f);
        float var  = s2 * (1.f / 64.f) - mean * mean;
        float rstd = rsqrtf(var + 1e-5f);
        float y[4];
        y[0] = (v0 - mean) * rstd * gw4[0] + bw4[0];
        y[1] = (v1 - mean) * rstd * gw4[1] + bw4[1];
        y[2] = (v2 - mean) * rstd * gw4[2] + bw4[2];
        y[3] = (v3 - mean) * rstd * gw4[3] + bw4[3];
        if (!(r & 1)) {
          ylo[0] = y[0]; ylo[1] = y[1]; ylo[2] = y[2]; ylo[3] = y[3];
        } else {
          int rowg0 = brow + (wr << 6) + (mi << 4) + ((l >> 4) << 2) + r - 1;
          int b = rowg0 >> 11, n = rowg0 & 2047;
          unsigned short* base =
              dst + (((size_t)(b * 16 + h) << 11) + n) * 64 + (l & 15);
#pragma unroll
          for (int ni = 0; ni < 4; ++ni) {
            unsigned u = cvtpk(ylo[ni], y[ni]);
            base[ni * 16]      = (unsigned short)(u & 0xffffu);
            base[ni * 16 + 64] = (unsigned short)(u >> 16);
          }
        }
      }
    }
  } else {
    const int bb = brow >> 11;
    const int nblk = brow & 2047;
#pragma unroll
    for (int mi = 0; mi < 4; ++mi)
#pragma unroll
      for (int ni = 0; ni < 4; ++ni) {
        int n0 = nblk + (wr << 6) + (mi << 4) + ((l >> 4) << 2);
        int colg = bcol + (wc << 6) + (ni << 4) + (l & 15);
        int h = colg >> 6, d = colg & 63;
        unsigned u0 = cvtpk(acc[mi][ni][0], acc[mi][ni][1]);
        unsigned u1 = cvtpk(acc[mi][ni][2], acc[mi][ni][3]);
        int2 u; u.x = (int)u0; u.y = (int)u1;
        *reinterpret_cast<int2*>(
            &vtb[((size_t)(bb * 16 + h) * 64 + d) * 2048 + n0]) = u;
      }
  }
}

// ---------------------------------------------------------------------------
// Flash attention, swapped-QK^T 32x32, STATIC-BOUND softmax (no online max:
// per-head LN guarantees |s| <= 11.54 in log2 domain, so exp2(s) is safe),
// cvt_pk + permlane32_swap P-repack, LDS double-buffer, named-reg prefetch.
// ---------------------------------------------------------------------------
__global__ __launch_bounds__(256, 2)
void attn_fwd(const unsigned short* __restrict__ Q,
              const unsigned short* __restrict__ K,
              const unsigned short* __restrict__ Vt,
              unsigned short* __restrict__ O)
{
  __shared__ short Ks[2][64 * 64];
  __shared__ short Vs[2][64 * 64];
  const int tid = threadIdx.x, w = tid >> 6, l = tid & 63;
  const int lo5 = l & 31, hi = l >> 5;
  const int bh = blockIdx.y;
  const int qbase = blockIdx.x * 128 + w * 32;
  const unsigned short* Qg = Q + ((size_t)bh * 2048 + qbase) * 64;
  const unsigned short* Kg = K + (size_t)bh * 2048 * 64;
  const unsigned short* Vg = Vt + (size_t)bh * 64 * 2048;

  bf16x8 qf[4];
#pragma unroll
  for (int ks = 0; ks < 4; ++ks)
    qf[ks] = *reinterpret_cast<const bf16x8*>(Qg + lo5 * 64 + ks * 16 + hi * 8);

  f32x16 oc0 = zero16(), oc1 = zero16();
  float lsum = 0.f;

  const int srow = tid >> 3;            // 0..31
  const int sc8 = (tid & 7) * 8;
  const int swz0 = sc8 ^ ((srow & 7) * 8);

  int4 ka0, ka1, va0, va1;
  ka0 = *reinterpret_cast<const int4*>(Kg + srow * 64 + sc8);
  ka1 = *reinterpret_cast<const int4*>(Kg + (32 + srow) * 64 + sc8);
  va0 = *reinterpret_cast<const int4*>(Vg + (size_t)srow * 2048 + sc8);
  va1 = *reinterpret_cast<const int4*>(Vg + (size_t)(32 + srow) * 2048 + sc8);
  *reinterpret_cast<int4*>(&Ks[0][(srow << 6) + swz0]) = ka0;
  *reinterpret_cast<int4*>(&Ks[0][((32 + srow) << 6) + swz0]) = ka1;
  *reinterpret_cast<int4*>(&Vs[0][(srow << 6) + swz0]) = va0;
  *reinterpret_cast<int4*>(&Vs[0][((32 + srow) << 6) + swz0]) = va1;
  __syncthreads();

  // strength-reduced prefetch pointers (next tile)
  const unsigned short* kp = Kg + 4096 + srow * 64 + sc8;
  const unsigned short* vp = Vg + 64 + (size_t)srow * 2048 + sc8;

  for (int it = 0; it < 32; ++it) {
    const int cur = it & 1;
    const short* Kc = Ks[cur];
    const short* Vc = Vs[cur];

    if (it < 31) {
      ka0 = *reinterpret_cast<const int4*>(kp);
      ka1 = *reinterpret_cast<const int4*>(kp + 2048);
      va0 = *reinterpret_cast<const int4*>(vp);
      va1 = *reinterpret_cast<const int4*>(vp + 65536);
      kp += 4096; vp += 64;
    }

    // QK^T (swapped): S[q=col][j=row], log2 domain
    f32x16 s0 = zero16(), s1 = zero16();
    __builtin_amdgcn_s_setprio(1);
#pragma unroll
    for (int ks = 0; ks < 4; ++ks) {
      const int colc = (16 * ks + 8 * hi) ^ ((lo5 & 7) << 3);
      bf16x8 k0 = *reinterpret_cast<const bf16x8*>(&Kc[(lo5 << 6) + colc]);
      s0 = mfma32(k0, qf[ks], s0);
      bf16x8 k1 = *reinterpret_cast<const bf16x8*>(&Kc[((32 + lo5) << 6) + colc]);
      s1 = mfma32(k1, qf[ks], s1);
    }
    __builtin_amdgcn_s_setprio(0);

    // static softmax: P = exp2(s) directly (|s| <= 11.54 guaranteed by LN)
    auto pvsub = [&](const f32x16& sv, int jbase) {
      float p0[16];
#pragma unroll
      for (int r = 0; r < 16; ++r) p0[r] = exp2f(sv[r]);
      lsum += (((p0[0] + p0[1]) + (p0[2] + p0[3])) +
               ((p0[4] + p0[5]) + (p0[6] + p0[7]))) +
              (((p0[8] + p0[9]) + (p0[10] + p0[11])) +
               ((p0[12] + p0[13]) + (p0[14] + p0[15])));
#pragma unroll
      for (int f = 0; f < 2; ++f) {
        unsigned x  = cvtpk(p0[8 * f + 0], p0[8 * f + 1]);
        unsigned zz = cvtpk(p0[8 * f + 2], p0[8 * f + 3]);
        unsigned y  = cvtpk(p0[8 * f + 4], p0[8 * f + 5]);
        unsigned ww = cvtpk(p0[8 * f + 6], p0[8 * f + 7]);
        pl32swap(x, y);
        pl32swap(zz, ww);
        bf16x8 pa = mk8(x, zz, y, ww);
        const int colc = (jbase + 16 * f + 8 * hi);
        bf16x8 v0 = *reinterpret_cast<const bf16x8*>(
            &Vc[(lo5 << 6) + (colc ^ ((lo5 & 7) << 3))]);
        bf16x8 v1 = *reinterpret_cast<const bf16x8*>(
            &Vc[((32 + lo5) << 6) + (colc ^ ((lo5 & 7) << 3))]);
        __builtin_amdgcn_s_setprio(1);
        oc0 = mfma32(pa, v0, oc0);
        oc1 = mfma32(pa, v1, oc1);
        __builtin_amdgcn_s_setprio(0);
      }
    };
    pvsub(s0, 0);
    pvsub(s1, 32);

    if (it < 31) {
      const int nb = cur ^ 1;
      *reinterpret_cast<int4*>(&Ks[nb][(srow << 6) + swz0]) = ka0;
      *reinterpret_cast<int4*>(&Ks[nb][((32 + srow) << 6) + swz0]) = ka1;
      *reinterpret_cast<int4*>(&Vs[nb][(srow << 6) + swz0]) = va0;
      *reinterpret_cast<int4*>(&Vs[nb][((32 + srow) << 6) + swz0]) = va1;
    }
    __syncthreads();
  }

  lsum += __shfl_xor(lsum, 32);
  float inv = 1.f / lsum;
  unsigned short* Og = O + ((size_t)(bh >> 4) * 2048 + qbase) * 1024 + (bh & 15) * 64;
#pragma unroll
  for (int r = 0; r < 16; ++r) {
    int qrow = (r & 3) + 8 * (r >> 2) + 4 * hi;
    float ir = __shfl(inv, qrow);
    Og[qrow * 1024 + lo5]      = f2bf(oc0[r] * ir);
    Og[qrow * 1024 + 32 + lo5] = f2bf(oc1[r] * ir);
  }
}

// ---------------------------------------------------------------------------
// Output projection (m97 structure): out = Ocat @ Wp^T + bp, fp32 out.
// ---------------------------------------------------------------------------
__global__ __launch_bounds__(256, 2)
void gemm_out_bf(const unsigned short* __restrict__ ob,
                 const unsigned short* __restrict__ wpb,
                 const float* __restrict__ bp, float* __restrict__ out)
{
  __shared__ short As[128 * 64];
  __shared__ short Bs[128 * 64];
  const int tid = threadIdx.x;
  const int l = tid & 63, w = tid >> 6;
  const int wr = w >> 1, wc = w & 1;
  const int brow = blockIdx.y * 128, bcol = blockIdx.x * 128;

  const f32x4 zero = {0.f, 0.f, 0.f, 0.f};
  f32x4 acc[4][4];
#pragma unroll
  for (int mi = 0; mi < 4; ++mi)
#pragma unroll
    for (int ni = 0; ni < 4; ++ni) acc[mi][ni] = zero;

  const int srow = w * 32 + (l >> 3);
  const int scol = (l & 7) * 8;

  for (int kt = 0; kt < 16; ++kt) {
    const unsigned short* ga = ob + (size_t)(brow + srow) * 1024 + kt * 64 + scol;
    const unsigned short* gb = wpb + (size_t)(bcol + srow) * 1024 + kt * 64 + scol;
#pragma unroll
    for (int i = 0; i < 4; ++i) {
      gl16(ga + (size_t)i * 8 * 1024, &As[(w * 32 + i * 8) * 64]);
      gl16(gb + (size_t)i * 8 * 1024, &Bs[(w * 32 + i * 8) * 64]);
    }
    __syncthreads();
#pragma unroll
    for (int kk = 0; kk < 2; ++kk) {
      const int k0 = kk * 32 + ((l >> 4) << 3);
      bf16x8 af[4], bfr[4];
#pragma unroll
      for (int mi = 0; mi < 4; ++mi)
        af[mi] = *reinterpret_cast<const bf16x8*>(
            &As[((wr << 6) + (mi << 4) + (l & 15)) * 64 + k0]);
#pragma unroll
      for (int ni = 0; ni < 4; ++ni)
        bfr[ni] = *reinterpret_cast<const bf16x8*>(
            &Bs[((wc << 6) + (ni << 4) + (l & 15)) * 64 + k0]);
#pragma unroll
      for (int mi = 0; mi < 4; ++mi)
#pragma unroll
        for (int ni = 0; ni < 4; ++ni)
          acc[mi][ni] = mfma16(af[mi], bfr[ni], acc[mi][ni]);
    }
    __syncthreads();
  }

  float bias[4];
#pragma unroll
  for (int ni = 0; ni < 4; ++ni)
    bias[ni] = bp[bcol + (wc << 6) + (ni << 4) + (l & 15)];
#pragma unroll
  for (int mi = 0; mi < 4; ++mi)
#pragma unroll
    for (int ni = 0; ni < 4; ++ni)
#pragma unroll
      for (int r = 0; r < 4; ++r) {
        int rowg = brow + (wr << 6) + (mi << 4) + ((l >> 4) << 2) + r;
        int colg = bcol + (wc << 6) + (ni << 4) + (l & 15);
        out[(size_t)rowg * 1024 + colg] = acc[mi][ni][r] + bias[ni];
      }
}

// ---------------------------------------------------------------------------
extern "C" void kernel_launch(void* const* d_in, const int* in_sizes, int n_in,
                              void* d_out, int out_size, void* d_ws, size_t ws_size,
                              hipStream_t stream)
{
  const float* x1 = (const float*)d_in[0];
  const float* x2 = (const float*)d_in[1];
  const float* Wq = (const float*)d_in[2];
  const float* Wk = (const float*)d_in[3];
  const float* Wv = (const float*)d_in[4];
  const float* Wp = (const float*)d_in[5];
  const float* bp = (const float*)d_in[6];
  const float* lg = (const float*)d_in[7];
  const float* lb = (const float*)d_in[8];

  char* wsb = (char*)d_ws;
  unsigned short* xb   = (unsigned short*)wsb;             // 24 MiB (12M ushort)
  unsigned short* qb   = (unsigned short*)(wsb + 25165824);// 8 MiB
  unsigned short* kb   = qb + 4194304;                     // 8 MiB
  unsigned short* vtb  = kb + 4194304;                     // 8 MiB (V^T)
  unsigned short* obuf = vtb + 4194304;                    // 8 MiB
  float* out = (float*)d_out;

  conv_bf16<<<6144, 256, 0, stream>>>(x1, x2, Wq, Wk, Wv, Wp, xb);
  gemm_qkv_bf<<<dim3(8, 32, 3), 256, 0, stream>>>(xb, lg, lb, qb, kb, vtb);
  attn_fwd<<<dim3(16, 32), 256, 0, stream>>>(qb, kb, vtb, obuf);
  gemm_out_bf<<<dim3(8, 32), 256, 0, stream>>>(obuf,
      xb + 11534336, bp, out);
}

// Round 9
// 130.331 us; speedup vs baseline: 1.4309x; 1.0315x over previous
//
#include <hip/hip_runtime.h>

#define DEV static __device__ __forceinline__

using bf16x8 = __attribute__((ext_vector_type(8))) short;
using f32x4  = __attribute__((ext_vector_type(4))) float;
using f32x16 = __attribute__((ext_vector_type(16))) float;

#if __has_builtin(__builtin_amdgcn_exp2f)
#define EXP2(x) __builtin_amdgcn_exp2f(x)
#else
#define EXP2(x) exp2f(x)
#endif

DEV unsigned short f2bf(float f) {
  union { float f; unsigned u; } v; v.f = f;
  return (unsigned short)((v.u + 0x7fffu + ((v.u >> 16) & 1u)) >> 16);
}
DEV unsigned pk2(float lo, float hi) {
  return (unsigned)f2bf(lo) | ((unsigned)f2bf(hi) << 16);
}
// single-instruction packed fp32->bf16 (RNE)
DEV unsigned cvtpk(float lo, float hi) {
  unsigned r;
  asm("v_cvt_pk_bf16_f32 %0, %1, %2" : "=v"(r) : "v"(lo), "v"(hi));
  return r;
}
// swap: a_new=[a_lo,b_lo], b_new=[a_hi,b_hi] across lane halves
DEV void pl32swap(unsigned &a, unsigned &b) {
  asm("v_permlane32_swap_b32 %0, %1" : "+v"(a), "+v"(b));
}
DEV bf16x8 mk8(unsigned a, unsigned b, unsigned c, unsigned d) {
  union { unsigned u[4]; bf16x8 v; } t;
  t.u[0] = a; t.u[1] = b; t.u[2] = c; t.u[3] = d;
  return t.v;
}
DEV f32x4 mfma16(bf16x8 a, bf16x8 b, f32x4 c) {
  return __builtin_amdgcn_mfma_f32_16x16x32_bf16(a, b, c, 0, 0, 0);
}
DEV f32x16 mfma32(bf16x8 a, bf16x8 b, f32x16 c) {
  return __builtin_amdgcn_mfma_f32_32x32x16_bf16(a, b, c, 0, 0, 0);
}
DEV f32x16 zero16() {
  f32x16 z;
#pragma unroll
  for (int i = 0; i < 16; ++i) z[i] = 0.f;
  return z;
}

typedef const __attribute__((address_space(1))) unsigned int* gas1;
typedef __attribute__((address_space(3))) unsigned int* las3;
DEV void gl16(const void* g, void* l) {
  __builtin_amdgcn_global_load_lds((gas1)g, (las3)l, 16, 0, 0);
}

// ---------------------------------------------------------------------------
// fp32 -> bf16 pre-convert: x1(4M) x2(4M) Wq Wk Wv Wp (1M each) -> 12M ushort.
// ---------------------------------------------------------------------------
__global__ __launch_bounds__(256, 8)
void conv_bf16(const float* __restrict__ x1, const float* __restrict__ x2,
               const float* __restrict__ Wq, const float* __restrict__ Wk,
               const float* __restrict__ Wv, const float* __restrict__ Wp,
               unsigned short* __restrict__ o)
{
  size_t e = ((size_t)blockIdx.x * 256 + threadIdx.x) * 8;
  const float* s; size_t off;
  if (e < 4194304u)       { s = x1; off = e; }
  else if (e < 8388608u)  { s = x2; off = e - 4194304u; }
  else if (e < 9437184u)  { s = Wq; off = e - 8388608u; }
  else if (e < 10485760u) { s = Wk; off = e - 9437184u; }
  else if (e < 11534336u) { s = Wv; off = e - 10485760u; }
  else                    { s = Wp; off = e - 11534336u; }
  const float4* p = reinterpret_cast<const float4*>(s + off);
  float4 a = p[0], b = p[1];
  int4 r;
  r.x = (int)cvtpk(a.x, a.y); r.y = (int)cvtpk(a.z, a.w);
  r.z = (int)cvtpk(b.x, b.y); r.w = (int)cvtpk(b.z, b.w);
  *reinterpret_cast<int4*>(o + e) = r;
}

// ---------------------------------------------------------------------------
// Fused QKV GEMM (m97 structure) + fused per-head LayerNorm epilogue.
// XCD-aware tile swizzle: each XCD owns contiguous A-row panels.
// z=0 -> qb bf16 [B,H,N,64], LN'd and scaled by 0.125*log2e
// z=1 -> kb bf16 [B,H,M,64], LN'd
// z=2 -> vtb bf16 [B,H,D,M] (V transposed)
// ---------------------------------------------------------------------------
__global__ __launch_bounds__(256, 2)
void gemm_qkv_bf(const unsigned short* __restrict__ xb,
                 const float* __restrict__ lg, const float* __restrict__ lb,
                 unsigned short* __restrict__ qb, unsigned short* __restrict__ kb,
                 unsigned short* __restrict__ vtb)
{
  __shared__ short As[128 * 64];
  __shared__ short Bs[128 * 64];
  const int tid = threadIdx.x;
  const int l = tid & 63, w = tid >> 6;
  const int wr = w >> 1, wc = w & 1;
  const int z = blockIdx.z;
  const unsigned short* A = (z == 0) ? xb : (xb + 4194304);
  const unsigned short* W = xb + 8388608 + (size_t)z * 1048576;
  // XCD swizzle (bijective on 256 = 8*32): hardware block id -> logical tile
  const int id = blockIdx.x + (blockIdx.y << 3);
  const int tl = ((id & 7) << 5) | (id >> 3);
  const int bx = tl & 7, by = tl >> 3;
  const int brow = by * 128, bcol = bx * 128;

  const f32x4 zero = {0.f, 0.f, 0.f, 0.f};
  f32x4 acc[4][4];
#pragma unroll
  for (int mi = 0; mi < 4; ++mi)
#pragma unroll
    for (int ni = 0; ni < 4; ++ni) acc[mi][ni] = zero;

  const int srow = w * 32 + (l >> 3);
  const int scol = (l & 7) * 8;

  for (int kt = 0; kt < 16; ++kt) {
    const unsigned short* ga = A + (size_t)(brow + srow) * 1024 + kt * 64 + scol;
    const unsigned short* gb = W + (size_t)(bcol + srow) * 1024 + kt * 64 + scol;
#pragma unroll
    for (int i = 0; i < 4; ++i) {
      gl16(ga + (size_t)i * 8 * 1024, &As[(w * 32 + i * 8) * 64]);
      gl16(gb + (size_t)i * 8 * 1024, &Bs[(w * 32 + i * 8) * 64]);
    }
    __syncthreads();
#pragma unroll
    for (int kk = 0; kk < 2; ++kk) {
      const int k0 = kk * 32 + ((l >> 4) << 3);
      bf16x8 af[4], bfr[4];
#pragma unroll
      for (int mi = 0; mi < 4; ++mi)
        af[mi] = *reinterpret_cast<const bf16x8*>(
            &As[((wr << 6) + (mi << 4) + (l & 15)) * 64 + k0]);
#pragma unroll
      for (int ni = 0; ni < 4; ++ni)
        bfr[ni] = *reinterpret_cast<const bf16x8*>(
            &Bs[((wc << 6) + (ni << 4) + (l & 15)) * 64 + k0]);
#pragma unroll
      for (int mi = 0; mi < 4; ++mi)
#pragma unroll
        for (int ni = 0; ni < 4; ++ni)
          acc[mi][ni] = mfma16(af[mi], bfr[ni], acc[mi][ni]);
    }
    __syncthreads();
  }

  if (z < 2) {
    // fused per-head LayerNorm: this wave's 64 cols == one full head
    unsigned short* dst = (z == 0) ? qb : kb;
    const float scl = (z == 0) ? 0.18033688011112042f : 1.0f; // 0.125*log2(e)
    const int h = bx * 2 + wc;
    float gw4[4], bw4[4];
#pragma unroll
    for (int ni = 0; ni < 4; ++ni) {
      gw4[ni] = lg[ni * 16 + (l & 15)] * scl;
      bw4[ni] = lb[ni * 16 + (l & 15)] * scl;
    }
#pragma unroll
    for (int mi = 0; mi < 4; ++mi) {
      float ylo[4];
#pragma unroll
      for (int r = 0; r < 4; ++r) {
        float v0 = acc[mi][0][r], v1 = acc[mi][1][r];
        float v2 = acc[mi][2][r], v3 = acc[mi][3][r];
        float s  = (v0 + v1) + (v2 + v3);
        float s2 = (v0 * v0 + v1 * v1) + (v2 * v2 + v3 * v3);
#pragma unroll
        for (int off = 1; off < 16; off <<= 1) {
          s  += __shfl_xor(s, off);
          s2 += __shfl_xor(s2, off);
        }
        float mean = s * (1.f / 64.f);
        float var  = s2 * (1.f / 64.f) - mean * mean;
        float rstd = rsqrtf(var + 1e-5f);
        float y[4];
        y[0] = (v0 - mean) * rstd * gw4[0] + bw4[0];
        y[1] = (v1 - mean) * rstd * gw4[1] + bw4[1];
        y[2] = (v2 - mean) * rstd * gw4[2] + bw4[2];
        y[3] = (v3 - mean) * rstd * gw4[3] + bw4[3];
        if (!(r & 1)) {
          ylo[0] = y[0]; ylo[1] = y[1]; ylo[2] = y[2]; ylo[3] = y[3];
        } else {
          int rowg0 = brow + (wr << 6) + (mi << 4) + ((l >> 4) << 2) + r - 1;
          int b = rowg0 >> 11, n = rowg0 & 2047;
          unsigned short* base =
              dst + (((size_t)(b * 16 + h) << 11) + n) * 64 + (l & 15);
#pragma unroll
          for (int ni = 0; ni < 4; ++ni) {
            unsigned u = cvtpk(ylo[ni], y[ni]);
            base[ni * 16]      = (unsigned short)(u & 0xffffu);
            base[ni * 16 + 64] = (unsigned short)(u >> 16);
          }
        }
      }
    }
  } else {
    const int bb = brow >> 11;
    const int nblk = brow & 2047;
#pragma unroll
    for (int mi = 0; mi < 4; ++mi)
#pragma unroll
      for (int ni = 0; ni < 4; ++ni) {
        int n0 = nblk + (wr << 6) + (mi << 4) + ((l >> 4) << 2);
        int colg = bcol + (wc << 6) + (ni << 4) + (l & 15);
        int h = colg >> 6, d = colg & 63;
        unsigned u0 = cvtpk(acc[mi][ni][0], acc[mi][ni][1]);
        unsigned u1 = cvtpk(acc[mi][ni][2], acc[mi][ni][3]);
        int2 u; u.x = (int)u0; u.y = (int)u1;
        *reinterpret_cast<int2*>(
            &vtb[((size_t)(bb * 16 + h) * 64 + d) * 2048 + n0]) = u;
      }
  }
}

// ---------------------------------------------------------------------------
// Flash attention, swapped-QK^T 32x32, static-bound exp2 softmax (no max:
// per-head LN bounds |s| <= 11.54 in log2 domain), XOR-swizzled pitch-64 LDS
// (b128 staging, 16B-aligned), LDS double-buffer, named-reg prefetch.
// 2-wave blocks (64 q-rows) -> 4 blocks/CU for cross-block overlap.
// ---------------------------------------------------------------------------
__global__ __launch_bounds__(128)
void attn_fwd(const unsigned short* __restrict__ Q,
              const unsigned short* __restrict__ K,
              const unsigned short* __restrict__ Vt,
              unsigned short* __restrict__ O)
{
  __shared__ short Ks[2][64 * 64];
  __shared__ short Vs[2][64 * 64];
  const int tid = threadIdx.x, w = tid >> 6, l = tid & 63;
  const int lo5 = l & 31, hi = l >> 5;
  const int bh = blockIdx.y;
  const int qbase = blockIdx.x * 64 + w * 32;
  const unsigned short* Qg = Q + ((size_t)bh * 2048 + qbase) * 64;
  const unsigned short* Kg = K + (size_t)bh * 2048 * 64;
  const unsigned short* Vg = Vt + (size_t)bh * 64 * 2048;

  bf16x8 qf[4];
#pragma unroll
  for (int ks = 0; ks < 4; ++ks)
    qf[ks] = *reinterpret_cast<const bf16x8*>(Qg + lo5 * 64 + ks * 16 + hi * 8);

  f32x16 oc0 = zero16(), oc1 = zero16();
  float lsum = 0.f;

  // staging: 128 threads; thread covers rows srow+16g (g=0..3), 16B at sc8.
  // XOR term identical for all 4 rows since they differ by multiples of 16.
  const int srow = tid >> 3;                  // 0..15
  const int sc8 = (tid & 7) * 8;
  const int swz = sc8 ^ ((srow & 7) << 3);

  int4 ka0, ka1, ka2, ka3, va0, va1, va2, va3;
  ka0 = *reinterpret_cast<const int4*>(Kg + (srow)      * 64 + sc8);
  ka1 = *reinterpret_cast<const int4*>(Kg + (srow + 16) * 64 + sc8);
  ka2 = *reinterpret_cast<const int4*>(Kg + (srow + 32) * 64 + sc8);
  ka3 = *reinterpret_cast<const int4*>(Kg + (srow + 48) * 64 + sc8);
  va0 = *reinterpret_cast<const int4*>(Vg + (size_t)(srow)      * 2048 + sc8);
  va1 = *reinterpret_cast<const int4*>(Vg + (size_t)(srow + 16) * 2048 + sc8);
  va2 = *reinterpret_cast<const int4*>(Vg + (size_t)(srow + 32) * 2048 + sc8);
  va3 = *reinterpret_cast<const int4*>(Vg + (size_t)(srow + 48) * 2048 + sc8);
  *reinterpret_cast<int4*>(&Ks[0][((srow)      << 6) + swz]) = ka0;
  *reinterpret_cast<int4*>(&Ks[0][((srow + 16) << 6) + swz]) = ka1;
  *reinterpret_cast<int4*>(&Ks[0][((srow + 32) << 6) + swz]) = ka2;
  *reinterpret_cast<int4*>(&Ks[0][((srow + 48) << 6) + swz]) = ka3;
  *reinterpret_cast<int4*>(&Vs[0][((srow)      << 6) + swz]) = va0;
  *reinterpret_cast<int4*>(&Vs[0][((srow + 16) << 6) + swz]) = va1;
  *reinterpret_cast<int4*>(&Vs[0][((srow + 32) << 6) + swz]) = va2;
  *reinterpret_cast<int4*>(&Vs[0][((srow + 48) << 6) + swz]) = va3;
  __syncthreads();

  // strength-reduced prefetch pointers (next tile)
  const unsigned short* kp = Kg + 4096 + srow * 64 + sc8;
  const unsigned short* vp = Vg + 64 + (size_t)srow * 2048 + sc8;

  for (int it = 0; it < 32; ++it) {
    const int cur = it & 1;
    const short* Kc = Ks[cur];
    const short* Vc = Vs[cur];

    if (it < 31) {   // issue next-tile loads; latency hides under compute
      ka0 = *reinterpret_cast<const int4*>(kp);
      ka1 = *reinterpret_cast<const int4*>(kp + 1024);
      ka2 = *reinterpret_cast<const int4*>(kp + 2048);
      ka3 = *reinterpret_cast<const int4*>(kp + 3072);
      va0 = *reinterpret_cast<const int4*>(vp);
      va1 = *reinterpret_cast<const int4*>(vp + 32768);
      va2 = *reinterpret_cast<const int4*>(vp + 65536);
      va3 = *reinterpret_cast<const int4*>(vp + 98304);
      kp += 4096; vp += 64;
    }

    // QK^T (swapped): S[q=col][j=row], log2 domain
    f32x16 s0 = zero16(), s1 = zero16();
    __builtin_amdgcn_s_setprio(1);
#pragma unroll
    for (int ks = 0; ks < 4; ++ks) {
      const int colc = (16 * ks + 8 * hi) ^ ((lo5 & 7) << 3);
      bf16x8 k0 = *reinterpret_cast<const bf16x8*>(&Kc[(lo5 << 6) + colc]);
      s0 = mfma32(k0, qf[ks], s0);
      bf16x8 k1 = *reinterpret_cast<const bf16x8*>(&Kc[((32 + lo5) << 6) + colc]);
      s1 = mfma32(k1, qf[ks], s1);
    }
    __builtin_amdgcn_s_setprio(0);

    // static softmax: P = exp2(s) directly (|s| <= 11.54 guaranteed by LN)
    auto pvsub = [&](const f32x16& sv, int jbase) {
      float p0[16];
#pragma unroll
      for (int r = 0; r < 16; ++r) p0[r] = EXP2(sv[r]);
      lsum += (((p0[0] + p0[1]) + (p0[2] + p0[3])) +
               ((p0[4] + p0[5]) + (p0[6] + p0[7]))) +
              (((p0[8] + p0[9]) + (p0[10] + p0[11])) +
               ((p0[12] + p0[13]) + (p0[14] + p0[15])));
#pragma unroll
      for (int f = 0; f < 2; ++f) {
        unsigned x  = cvtpk(p0[8 * f + 0], p0[8 * f + 1]);
        unsigned zz = cvtpk(p0[8 * f + 2], p0[8 * f + 3]);
        unsigned y  = cvtpk(p0[8 * f + 4], p0[8 * f + 5]);
        unsigned ww = cvtpk(p0[8 * f + 6], p0[8 * f + 7]);
        pl32swap(x, y);
        pl32swap(zz, ww);
        bf16x8 pa = mk8(x, zz, y, ww);
        const int colc = (jbase + 16 * f + 8 * hi);
        bf16x8 v0 = *reinterpret_cast<const bf16x8*>(
            &Vc[(lo5 << 6) + (colc ^ ((lo5 & 7) << 3))]);
        bf16x8 v1 = *reinterpret_cast<const bf16x8*>(
            &Vc[((32 + lo5) << 6) + (colc ^ ((lo5 & 7) << 3))]);
        __builtin_amdgcn_s_setprio(1);
        oc0 = mfma32(pa, v0, oc0);
        oc1 = mfma32(pa, v1, oc1);
        __builtin_amdgcn_s_setprio(0);
      }
    };
    pvsub(s0, 0);
    pvsub(s1, 32);

    if (it < 31) {   // write next tile into the other buffer (no hazard)
      const int nb = cur ^ 1;
      *reinterpret_cast<int4*>(&Ks[nb][((srow)      << 6) + swz]) = ka0;
      *reinterpret_cast<int4*>(&Ks[nb][((srow + 16) << 6) + swz]) = ka1;
      *reinterpret_cast<int4*>(&Ks[nb][((srow + 32) << 6) + swz]) = ka2;
      *reinterpret_cast<int4*>(&Ks[nb][((srow + 48) << 6) + swz]) = ka3;
      *reinterpret_cast<int4*>(&Vs[nb][((srow)      << 6) + swz]) = va0;
      *reinterpret_cast<int4*>(&Vs[nb][((srow + 16) << 6) + swz]) = va1;
      *reinterpret_cast<int4*>(&Vs[nb][((srow + 32) << 6) + swz]) = va2;
      *reinterpret_cast<int4*>(&Vs[nb][((srow + 48) << 6) + swz]) = va3;
    }
    __syncthreads();   // single barrier: covers buffer swap both ways
  }

  lsum += __shfl_xor(lsum, 32);
  float inv = 1.f / lsum;
  unsigned short* Og = O + ((size_t)(bh >> 4) * 2048 + qbase) * 1024 + (bh & 15) * 64;
#pragma unroll
  for (int r = 0; r < 16; ++r) {
    int qrow = (r & 3) + 8 * (r >> 2) + 4 * hi;
    float ir = __shfl(inv, qrow);
    Og[qrow * 1024 + lo5]      = f2bf(oc0[r] * ir);
    Og[qrow * 1024 + 32 + lo5] = f2bf(oc1[r] * ir);
  }
}

// ---------------------------------------------------------------------------
// Output projection (m97 structure): out = Ocat @ Wp^T + bp, fp32 out.
// XCD-aware tile swizzle as in gemm_qkv_bf.
// ---------------------------------------------------------------------------
__global__ __launch_bounds__(256, 2)
void gemm_out_bf(const unsigned short* __restrict__ ob,
                 const unsigned short* __restrict__ wpb,
                 const float* __restrict__ bp, float* __restrict__ out)
{
  __shared__ short As[128 * 64];
  __shared__ short Bs[128 * 64];
  const int tid = threadIdx.x;
  const int l = tid & 63, w = tid >> 6;
  const int wr = w >> 1, wc = w & 1;
  const int id = blockIdx.x + (blockIdx.y << 3);
  const int tl = ((id & 7) << 5) | (id >> 3);
  const int brow = (tl >> 3) * 128, bcol = (tl & 7) * 128;

  const f32x4 zero = {0.f, 0.f, 0.f, 0.f};
  f32x4 acc[4][4];
#pragma unroll
  for (int mi = 0; mi < 4; ++mi)
#pragma unroll
    for (int ni = 0; ni < 4; ++ni) acc[mi][ni] = zero;

  const int srow = w * 32 + (l >> 3);
  const int scol = (l & 7) * 8;

  for (int kt = 0; kt < 16; ++kt) {
    const unsigned short* ga = ob + (size_t)(brow + srow) * 1024 + kt * 64 + scol;
    const unsigned short* gb = wpb + (size_t)(bcol + srow) * 1024 + kt * 64 + scol;
#pragma unroll
    for (int i = 0; i < 4; ++i) {
      gl16(ga + (size_t)i * 8 * 1024, &As[(w * 32 + i * 8) * 64]);
      gl16(gb + (size_t)i * 8 * 1024, &Bs[(w * 32 + i * 8) * 64]);
    }
    __syncthreads();
#pragma unroll
    for (int kk = 0; kk < 2; ++kk) {
      const int k0 = kk * 32 + ((l >> 4) << 3);
      bf16x8 af[4], bfr[4];
#pragma unroll
      for (int mi = 0; mi < 4; ++mi)
        af[mi] = *reinterpret_cast<const bf16x8*>(
            &As[((wr << 6) + (mi << 4) + (l & 15)) * 64 + k0]);
#pragma unroll
      for (int ni = 0; ni < 4; ++ni)
        bfr[ni] = *reinterpret_cast<const bf16x8*>(
            &Bs[((wc << 6) + (ni << 4) + (l & 15)) * 64 + k0]);
#pragma unroll
      for (int mi = 0; mi < 4; ++mi)
#pragma unroll
        for (int ni = 0; ni < 4; ++ni)
          acc[mi][ni] = mfma16(af[mi], bfr[ni], acc[mi][ni]);
    }
    __syncthreads();
  }

  float bias[4];
#pragma unroll
  for (int ni = 0; ni < 4; ++ni)
    bias[ni] = bp[bcol + (wc << 6) + (ni << 4) + (l & 15)];
#pragma unroll
  for (int mi = 0; mi < 4; ++mi)
#pragma unroll
    for (int ni = 0; ni < 4; ++ni)
#pragma unroll
      for (int r = 0; r < 4; ++r) {
        int rowg = brow + (wr << 6) + (mi << 4) + ((l >> 4) << 2) + r;
        int colg = bcol + (wc << 6) + (ni << 4) + (l & 15);
        out[(size_t)rowg * 1024 + colg] = acc[mi][ni][r] + bias[ni];
      }
}

// ---------------------------------------------------------------------------
extern "C" void kernel_launch(void* const* d_in, const int* in_sizes, int n_in,
                              void* d_out, int out_size, void* d_ws, size_t ws_size,
                              hipStream_t stream)
{
  const float* x1 = (const float*)d_in[0];
  const float* x2 = (const float*)d_in[1];
  const float* Wq = (const float*)d_in[2];
  const float* Wk = (const float*)d_in[3];
  const float* Wv = (const float*)d_in[4];
  const float* Wp = (const float*)d_in[5];
  const float* bp = (const float*)d_in[6];
  const float* lg = (const float*)d_in[7];
  const float* lb = (const float*)d_in[8];

  char* wsb = (char*)d_ws;
  unsigned short* xb   = (unsigned short*)wsb;             // 24 MiB (12M ushort)
  unsigned short* qb   = (unsigned short*)(wsb + 25165824);// 8 MiB
  unsigned short* kb   = qb + 4194304;                     // 8 MiB
  unsigned short* vtb  = kb + 4194304;                     // 8 MiB (V^T)
  unsigned short* obuf = vtb + 4194304;                    // 8 MiB
  float* out = (float*)d_out;

  conv_bf16<<<6144, 256, 0, stream>>>(x1, x2, Wq, Wk, Wv, Wp, xb);
  gemm_qkv_bf<<<dim3(8, 32, 3), 256, 0, stream>>>(xb, lg, lb, qb, kb, vtb);
  attn_fwd<<<dim3(32, 32), 128, 0, stream>>>(qb, kb, vtb, obuf);
  gemm_out_bf<<<dim3(8, 32), 256, 0, stream>>>(obuf,
      xb + 11534336, bp, out);
}